// Round 1
// baseline (601.801 us; speedup 1.0000x reference)
//
#include <hip/hip_runtime.h>

#define L_MAX 16
#define NCOL  289   // (L_MAX+1)^2
#define BPTS  64    // points per block (one wave)

// ---- compile-time prefactor table: F[l][m] = (-1)^m sqrt((2l+1)/(2pi) * (l-m)!/(l+m)!) ----
constexpr double csqrt(double x) {
  double g = x > 1.0 ? x : 1.0;
  for (int i = 0; i < 500; ++i) {
    double n = 0.5 * (g + x / g);
    if (n == g) break;
    g = n;
  }
  return g;
}
constexpr double cfact(int n) { double f = 1.0; for (int i = 2; i <= n; ++i) f *= (double)i; return f; }

struct FTab { float v[L_MAX + 1][L_MAX + 1]; };
constexpr FTab make_ftab() {
  FTab t{};
  for (int l = 0; l <= L_MAX; ++l)
    for (int m = 0; m <= l; ++m) {
      double val = ((m & 1) ? -1.0 : 1.0) *
        csqrt((2.0 * l + 1.0) / (2.0 * 3.14159265358979323846) * cfact(l - m) / cfact(l + m));
      t.v[l][m] = (float)val;
    }
  return t;
}
constexpr FTab FT = make_ftab();

__global__ __launch_bounds__(64)
void sh_kernel(const float* __restrict__ xyz, float* __restrict__ out, int npts) {
  // 64 rows x 289 cols, row stride exactly 289 so the buffer is LINEAR in the
  // same order as global memory -> coalesced float4 writeback.
  // LDS write banks: (lane*289 + col) % 32 = (lane+col)%32 -> 2 lanes/bank (free).
  __shared__ float lds[BPTS * NCOL];

  const int  lane   = threadIdx.x;
  const int  batch  = blockIdx.x;
  const long long p0 = (long long)batch * BPTS;
  const int  nvalid = min(BPTS, npts - (int)p0);
  const int  p      = (int)p0 + lane;

  if (lane < nvalid) {
    const float x = xyz[3 * p + 0];
    const float y = xyz[3 * p + 1];
    const float z = xyz[3 * p + 2];
    const float r2 = x * x + y * y + z * z;
    float* row = &lds[lane * NCOL];

    // c[m] + i s[m] = (x + i y)^m
    float cc[L_MAX + 1], ss[L_MAX + 1];
    cc[0] = 1.f; ss[0] = 0.f;
#pragma unroll
    for (int m = 1; m <= L_MAX; ++m) {
      cc[m] = x * cc[m - 1] - y * ss[m - 1];
      ss[m] = x * ss[m - 1] + y * cc[m - 1];
    }

    constexpr float INVS2 = 0.70710678118654752440f;

    // rolling Q rows; full unroll keeps every index compile-time (registers only)
    float Qm1[L_MAX + 1], Qm2[L_MAX + 1], cur[L_MAX + 1];
    Qm1[0] = 1.f;
    row[0] = FT.v[0][0] * INVS2;
#pragma unroll
    for (int l = 1; l <= L_MAX; ++l) {
      const float tl = (float)(2 * l - 1);
      cur[l]     = -tl * Qm1[l - 1];
      cur[l - 1] = tl * z * Qm1[l - 1];
#pragma unroll
      for (int m = l - 2; m >= 0; --m)
        cur[m] = (tl * z * Qm1[m] - (float)(l + m - 1) * r2 * Qm2[m]) * (1.f / (float)(l - m));

      const int base = l * l + l;
      row[base] = FT.v[l][0] * cur[0] * INVS2;
#pragma unroll
      for (int m = 1; m <= l; ++m) {
        const float b = FT.v[l][m] * cur[m];
        row[base - m] = b * ss[m];   // m < 0 columns
        row[base + m] = b * cc[m];   // m > 0 columns
      }
#pragma unroll
      for (int m = 0; m <= l; ++m) { Qm2[m] = Qm1[m]; Qm1[m] = cur[m]; }
    }
  }
  __syncthreads();

  // cooperative, fully-coalesced writeback of the contiguous 74 KB block
  const int ndw = nvalid * NCOL;
  float* dst = out + p0 * NCOL;
  const int nv4 = ndw & ~3;
  for (int base = lane * 4; base < nv4; base += 4 * BPTS) {
    float4 v = *reinterpret_cast<const float4*>(&lds[base]);
    *reinterpret_cast<float4*>(&dst[base]) = v;
  }
  for (int i = nv4 + lane; i < ndw; i += BPTS) dst[i] = lds[i];
}

extern "C" void kernel_launch(void* const* d_in, const int* in_sizes, int n_in,
                              void* d_out, int out_size, void* d_ws, size_t ws_size,
                              hipStream_t stream) {
  const float* xyz = (const float*)d_in[0];
  float* out = (float*)d_out;
  const int npts = in_sizes[0] / 3;
  const int nblocks = (npts + BPTS - 1) / BPTS;
  sh_kernel<<<nblocks, BPTS, 0, stream>>>(xyz, out, npts);
}